// Round 6
// baseline (979.261 us; speedup 1.0000x reference)
//
#include <hip/hip_runtime.h>
#include <cmath>

#define BB 2
#define SS_ 2048
#define EE 1024
#define CC 16

typedef __attribute__((ext_vector_type(8))) short short8v;
typedef __attribute__((ext_vector_type(4))) float floatx4;

__device__ __forceinline__ void split4(const float4 v, short4& h, short4& l)
{
    unsigned ux = __float_as_uint(v.x), uy = __float_as_uint(v.y);
    unsigned uz = __float_as_uint(v.z), uw = __float_as_uint(v.w);
    h.x = (short)(ux >> 16); h.y = (short)(uy >> 16);
    h.z = (short)(uz >> 16); h.w = (short)(uw >> 16);
    float lx = v.x - __uint_as_float(ux & 0xFFFF0000u);
    float ly = v.y - __uint_as_float(uy & 0xFFFF0000u);
    float lz = v.z - __uint_as_float(uz & 0xFFFF0000u);
    float lw = v.w - __uint_as_float(uw & 0xFFFF0000u);
    l.x = (short)(__float_as_uint(lx) >> 16);
    l.y = (short)(__float_as_uint(ly) >> 16);
    l.z = (short)(__float_as_uint(lz) >> 16);
    l.w = (short)(__float_as_uint(lw) >> 16);
}

// ---------------------------------------------------------------------------
// Split-bf16 MFMA GEMM, K-split + atomic epilogue: C += alpha * A @ B^T
// ---------------------------------------------------------------------------
#define BM 128
#define BN 128
#define BK 32
#define LDP 40

__launch_bounds__(256, 4)
__global__ void gemm_at(const float* __restrict__ A, const float* __restrict__ Bsrc,
                        float* __restrict__ C,
                        int K, int lda, int ldb, int ldc,
                        long sA, long sB, long sC, float alpha, int KS)
{
    __shared__ short sAh[BM * LDP], sAl[BM * LDP], sBh[BN * LDP], sBl[BN * LDP];
    const int z = blockIdx.z;
    const int bz = z / KS, ks = z % KS;
    const int klen = K / KS, kbase = ks * klen;
    A += (size_t)bz * sA; Bsrc += (size_t)bz * sB; C += (size_t)bz * sC;
    const int tid = threadIdx.x;
    const int m0 = blockIdx.y * BM, n0 = blockIdx.x * BN;

    const int lr0 = tid >> 3;
    const int kc0 = (tid & 7) * 4;
    const float* pa = A + (size_t)(m0 + lr0) * lda + kbase + kc0;
    const float* pb = Bsrc + (size_t)(n0 + lr0) * ldb + kbase + kc0;

    float4 ra[4], rb[4];
    #pragma unroll
    for (int c = 0; c < 4; ++c) {
        ra[c] = *(const float4*)(pa + (size_t)c * 32 * lda);
        rb[c] = *(const float4*)(pb + (size_t)c * 32 * ldb);
    }

    const int lane = tid & 63, wid = tid >> 6;
    const int wm = wid >> 1, wn = wid & 1;
    const int lr = lane & 15, qd = lane >> 4;
    const int arow = wm * 64 + lr;
    const int brow = wn * 64 + lr;
    const int koff = qd * 8;

    floatx4 acc[4][4];
    #pragma unroll
    for (int i = 0; i < 4; ++i)
        #pragma unroll
        for (int j = 0; j < 4; ++j)
            acc[i][j] = (floatx4){0.f, 0.f, 0.f, 0.f};

    for (int kt = 0; kt < klen; kt += BK) {
        __syncthreads();
        #pragma unroll
        for (int c = 0; c < 4; ++c) {
            const int row = lr0 + c * 32;
            short4 h, l;
            split4(ra[c], h, l);
            *(short4*)&sAh[row * LDP + kc0] = h;
            *(short4*)&sAl[row * LDP + kc0] = l;
            split4(rb[c], h, l);
            *(short4*)&sBh[row * LDP + kc0] = h;
            *(short4*)&sBl[row * LDP + kc0] = l;
        }
        __syncthreads();
        if (kt + BK < klen) {
            pa += BK; pb += BK;
            #pragma unroll
            for (int c = 0; c < 4; ++c) {
                ra[c] = *(const float4*)(pa + (size_t)c * 32 * lda);
                rb[c] = *(const float4*)(pb + (size_t)c * 32 * ldb);
            }
        }
        short8v ah[4], al[4], bh[4], bl[4];
        #pragma unroll
        for (int i = 0; i < 4; ++i) {
            ah[i] = *(const short8v*)&sAh[(arow + i * 16) * LDP + koff];
            al[i] = *(const short8v*)&sAl[(arow + i * 16) * LDP + koff];
            bh[i] = *(const short8v*)&sBh[(brow + i * 16) * LDP + koff];
            bl[i] = *(const short8v*)&sBl[(brow + i * 16) * LDP + koff];
        }
        #pragma unroll
        for (int i = 0; i < 4; ++i)
            #pragma unroll
            for (int j = 0; j < 4; ++j)
                acc[i][j] = __builtin_amdgcn_mfma_f32_16x16x32_bf16(ah[i], bh[j], acc[i][j], 0, 0, 0);
        #pragma unroll
        for (int i = 0; i < 4; ++i)
            #pragma unroll
            for (int j = 0; j < 4; ++j)
                acc[i][j] = __builtin_amdgcn_mfma_f32_16x16x32_bf16(ah[i], bl[j], acc[i][j], 0, 0, 0);
        #pragma unroll
        for (int i = 0; i < 4; ++i)
            #pragma unroll
            for (int j = 0; j < 4; ++j)
                acc[i][j] = __builtin_amdgcn_mfma_f32_16x16x32_bf16(al[i], bh[j], acc[i][j], 0, 0, 0);
    }

    #pragma unroll
    for (int i = 0; i < 4; ++i) {
        const int mbase = m0 + wm * 64 + i * 16 + qd * 4;
        #pragma unroll
        for (int j = 0; j < 4; ++j) {
            const int n = n0 + wn * 64 + j * 16 + lr;
            #pragma unroll
            for (int r = 0; r < 4; ++r)
                atomicAdd(&C[(size_t)(mbase + r) * ldc + n], alpha * acc[i][j][r]);
        }
    }
}

// ---------------------------------------------------------------------------
// sk48: C += A @ B, tall-skinny NT=48, bf16x3 MFMA. klen=512 fixed.
// grid (M/64, 1, Z*KS). Atomic epilogue (C pre-initialized).
// ---------------------------------------------------------------------------
__launch_bounds__(256, 4)
__global__ void sk48(const float* __restrict__ A, const float* __restrict__ B,
                     float* __restrict__ C, int lda,
                     long sA, long sB, long sC, int KS)
{
    __shared__ short sAh[64 * 40], sAl[64 * 40];
    __shared__ short sBh[48 * 40], sBl[48 * 40];
    const int z = blockIdx.z;
    const int zb = z / KS, ks = z % KS;
    const int kbase = ks * 512;
    A += (size_t)zb * sA; B += (size_t)zb * sB; C += (size_t)zb * sC;
    const int tid = threadIdx.x;
    const int m0 = blockIdx.x * 64;
    const int arow = tid >> 2, akc = (tid & 3) * 8;
    const int lane = tid & 63, w = tid >> 6;
    const int lr = lane & 15, qd = lane >> 4;

    floatx4 acc[3];
    #pragma unroll
    for (int j = 0; j < 3; ++j) acc[j] = (floatx4){0.f, 0.f, 0.f, 0.f};

    for (int kc = 0; kc < 512; kc += 32) {
        __syncthreads();
        {
            const float* pa = A + (size_t)(m0 + arow) * lda + kbase + kc + akc;
            float4 v0 = *(const float4*)pa, v1 = *(const float4*)(pa + 4);
            short4 h, l;
            split4(v0, h, l);
            *(short4*)&sAh[arow * 40 + akc] = h;
            *(short4*)&sAl[arow * 40 + akc] = l;
            split4(v1, h, l);
            *(short4*)&sAh[arow * 40 + akc + 4] = h;
            *(short4*)&sAl[arow * 40 + akc + 4] = l;
        }
        for (int lin = tid; lin < 384; lin += 256) {
            int kk = lin / 12, n4 = (lin % 12) * 4;
            float4 v = *(const float4*)(B + (size_t)(kbase + kc + kk) * 48 + n4);
            short4 h, l; split4(v, h, l);
            sBh[(n4 + 0) * 40 + kk] = h.x; sBh[(n4 + 1) * 40 + kk] = h.y;
            sBh[(n4 + 2) * 40 + kk] = h.z; sBh[(n4 + 3) * 40 + kk] = h.w;
            sBl[(n4 + 0) * 40 + kk] = l.x; sBl[(n4 + 1) * 40 + kk] = l.y;
            sBl[(n4 + 2) * 40 + kk] = l.z; sBl[(n4 + 3) * 40 + kk] = l.w;
        }
        __syncthreads();
        short8v ah = *(const short8v*)&sAh[(w * 16 + lr) * 40 + qd * 8];
        short8v al = *(const short8v*)&sAl[(w * 16 + lr) * 40 + qd * 8];
        #pragma unroll
        for (int j = 0; j < 3; ++j) {
            short8v bh = *(const short8v*)&sBh[(j * 16 + lr) * 40 + qd * 8];
            short8v bl = *(const short8v*)&sBl[(j * 16 + lr) * 40 + qd * 8];
            acc[j] = __builtin_amdgcn_mfma_f32_16x16x32_bf16(ah, bh, acc[j], 0, 0, 0);
            acc[j] = __builtin_amdgcn_mfma_f32_16x16x32_bf16(ah, bl, acc[j], 0, 0, 0);
            acc[j] = __builtin_amdgcn_mfma_f32_16x16x32_bf16(al, bh, acc[j], 0, 0, 0);
        }
    }
    #pragma unroll
    for (int j = 0; j < 3; ++j) {
        const int n = j * 16 + lr;
        const int mb = m0 + w * 16 + qd * 4;
        #pragma unroll
        for (int r = 0; r < 4; ++r)
            atomicAdd(&C[(size_t)(mb + r) * 48 + n], acc[j][r]);
    }
}

// ---------------------------------------------------------------------------
// skinny_fwd: merged forward transforms. grid (32, 1, 16).
// z<8: Tfr=MAT0@Uf, Tfi=MAT1@Uf (dual-A). z>=8: Tc=DCTD@Uc.
// M=2048/batch, K=2048, klen=512, NT=48.
// ---------------------------------------------------------------------------
__launch_bounds__(256, 4)
__global__ void skinny_fwd(const float* __restrict__ MAT0, const float* __restrict__ MAT1,
                           const float* __restrict__ DCTD,
                           const float* __restrict__ Uf, const float* __restrict__ Uc,
                           float* __restrict__ Tfr, float* __restrict__ Tfi,
                           float* __restrict__ Tc)
{
    __shared__ short sAh[2][64 * 40], sAl[2][64 * 40];
    __shared__ short sBh[48 * 40], sBl[48 * 40];
    const int z = blockIdx.z;
    const bool dual = (z < 8);
    const int zz = dual ? z : z - 8;
    const int zb = zz >> 2, ks = zz & 3;
    const int kbase = ks * 512;
    const float* A0 = dual ? MAT0 : DCTD;
    const float* Bp = (dual ? Uf : Uc) + (size_t)zb * 98304;
    float* C0 = (dual ? Tfr : Tc) + (size_t)zb * 98304;
    float* C1 = Tfi + (size_t)zb * 98304;

    const int tid = threadIdx.x;
    const int m0 = blockIdx.x * 64;
    const int arow = tid >> 2, akc = (tid & 3) * 8;
    const int lane = tid & 63, w = tid >> 6;
    const int lr = lane & 15, qd = lane >> 4;

    floatx4 acc0[3], acc1[3];
    #pragma unroll
    for (int j = 0; j < 3; ++j) {
        acc0[j] = (floatx4){0.f, 0.f, 0.f, 0.f};
        acc1[j] = (floatx4){0.f, 0.f, 0.f, 0.f};
    }

    for (int kc = 0; kc < 512; kc += 32) {
        __syncthreads();
        {
            const float* pa = A0 + (size_t)(m0 + arow) * 2048 + kbase + kc + akc;
            float4 v0 = *(const float4*)pa, v1 = *(const float4*)(pa + 4);
            short4 h, l;
            split4(v0, h, l);
            *(short4*)&sAh[0][arow * 40 + akc] = h;
            *(short4*)&sAl[0][arow * 40 + akc] = l;
            split4(v1, h, l);
            *(short4*)&sAh[0][arow * 40 + akc + 4] = h;
            *(short4*)&sAl[0][arow * 40 + akc + 4] = l;
        }
        if (dual) {
            const float* pa = MAT1 + (size_t)(m0 + arow) * 2048 + kbase + kc + akc;
            float4 v0 = *(const float4*)pa, v1 = *(const float4*)(pa + 4);
            short4 h, l;
            split4(v0, h, l);
            *(short4*)&sAh[1][arow * 40 + akc] = h;
            *(short4*)&sAl[1][arow * 40 + akc] = l;
            split4(v1, h, l);
            *(short4*)&sAh[1][arow * 40 + akc + 4] = h;
            *(short4*)&sAl[1][arow * 40 + akc + 4] = l;
        }
        for (int lin = tid; lin < 384; lin += 256) {
            int kk = lin / 12, n4 = (lin % 12) * 4;
            float4 v = *(const float4*)(Bp + (size_t)(kbase + kc + kk) * 48 + n4);
            short4 h, l; split4(v, h, l);
            sBh[(n4 + 0) * 40 + kk] = h.x; sBh[(n4 + 1) * 40 + kk] = h.y;
            sBh[(n4 + 2) * 40 + kk] = h.z; sBh[(n4 + 3) * 40 + kk] = h.w;
            sBl[(n4 + 0) * 40 + kk] = l.x; sBl[(n4 + 1) * 40 + kk] = l.y;
            sBl[(n4 + 2) * 40 + kk] = l.z; sBl[(n4 + 3) * 40 + kk] = l.w;
        }
        __syncthreads();
        short8v ah0 = *(const short8v*)&sAh[0][(w * 16 + lr) * 40 + qd * 8];
        short8v al0 = *(const short8v*)&sAl[0][(w * 16 + lr) * 40 + qd * 8];
        short8v bh[3], bl[3];
        #pragma unroll
        for (int j = 0; j < 3; ++j) {
            bh[j] = *(const short8v*)&sBh[(j * 16 + lr) * 40 + qd * 8];
            bl[j] = *(const short8v*)&sBl[(j * 16 + lr) * 40 + qd * 8];
        }
        #pragma unroll
        for (int j = 0; j < 3; ++j) {
            acc0[j] = __builtin_amdgcn_mfma_f32_16x16x32_bf16(ah0, bh[j], acc0[j], 0, 0, 0);
            acc0[j] = __builtin_amdgcn_mfma_f32_16x16x32_bf16(ah0, bl[j], acc0[j], 0, 0, 0);
            acc0[j] = __builtin_amdgcn_mfma_f32_16x16x32_bf16(al0, bh[j], acc0[j], 0, 0, 0);
        }
        if (dual) {
            short8v ah1 = *(const short8v*)&sAh[1][(w * 16 + lr) * 40 + qd * 8];
            short8v al1 = *(const short8v*)&sAl[1][(w * 16 + lr) * 40 + qd * 8];
            #pragma unroll
            for (int j = 0; j < 3; ++j) {
                acc1[j] = __builtin_amdgcn_mfma_f32_16x16x32_bf16(ah1, bh[j], acc1[j], 0, 0, 0);
                acc1[j] = __builtin_amdgcn_mfma_f32_16x16x32_bf16(ah1, bl[j], acc1[j], 0, 0, 0);
                acc1[j] = __builtin_amdgcn_mfma_f32_16x16x32_bf16(al1, bh[j], acc1[j], 0, 0, 0);
            }
        }
    }
    #pragma unroll
    for (int j = 0; j < 3; ++j) {
        const int n = j * 16 + lr;
        const int mb = m0 + w * 16 + qd * 4;
        #pragma unroll
        for (int r = 0; r < 4; ++r) {
            atomicAdd(&C0[(size_t)(mb + r) * 48 + n], acc0[j][r]);
            if (dual) atomicAdd(&C1[(size_t)(mb + r) * 48 + n], acc1[j][r]);
        }
    }
}

// ---------------------------------------------------------------------------
// skinny_inv: merged inverse transforms + Pt. grid (48, 1, 22).
// z<8: Rf += (1/2048)(MAT0@OFr + MAT1@OFi); z in [8,16): Rc += DCTI@Oc;
// z in [16,22): Pt_l += mha_iw @ fwT_l. NT=16.
// ---------------------------------------------------------------------------
__launch_bounds__(256, 4)
__global__ void skinny_inv(const float* __restrict__ MAT0, const float* __restrict__ MAT1,
                           const float* __restrict__ DCTI,
                           const float* __restrict__ OFr, const float* __restrict__ OFi,
                           const float* __restrict__ Oc,
                           const float* __restrict__ iw, const float* __restrict__ fwT,
                           float* __restrict__ Rf, float* __restrict__ Rc,
                           float* __restrict__ Pt)
{
    __shared__ short sAh[2][64 * 40], sAl[2][64 * 40];
    __shared__ short sBh[2][16 * 40], sBl[2][16 * 40];
    const int z = blockIdx.z;
    const int mode = (z < 8) ? 0 : ((z < 16) ? 1 : 2);
    if (mode < 2 && blockIdx.x >= 32) return;
    const float *A0, *A1 = nullptr, *B0, *B1 = nullptr;
    float* C; float alpha; int lda, ldc, kbase;
    if (mode == 0) {
        int zb = z >> 2, ks = z & 3;
        kbase = ks * 512; lda = 2048;
        A0 = MAT0; A1 = MAT1;
        B0 = OFr + (size_t)zb * 32768; B1 = OFi + (size_t)zb * 32768;
        C = Rf + (size_t)zb * 32768; ldc = 16; alpha = 1.f / 2048.f;
    } else if (mode == 1) {
        int zz = z - 8; int zb = zz >> 2, ks = zz & 3;
        kbase = ks * 512; lda = 2048;
        A0 = DCTI; B0 = Oc + (size_t)zb * 32768;
        C = Rc + (size_t)zb * 32768; ldc = 16; alpha = 1.f;
    } else {
        int zz = z - 16; int l = zz >> 1, ks = zz & 1;
        kbase = ks * 512; lda = 1024;
        A0 = iw; B0 = fwT + (size_t)l * 16384;
        C = Pt + (size_t)l * 52224; ldc = 17; alpha = 1.f;
    }
    const bool dual = (mode == 0);

    const int tid = threadIdx.x;
    const int m0 = blockIdx.x * 64;
    const int arow = tid >> 2, akc = (tid & 3) * 8;
    const int lane = tid & 63, w = tid >> 6;
    const int lr = lane & 15, qd = lane >> 4;

    floatx4 acc = (floatx4){0.f, 0.f, 0.f, 0.f};

    for (int kc = 0; kc < 512; kc += 32) {
        __syncthreads();
        {
            const float* pa = A0 + (size_t)(m0 + arow) * lda + kbase + kc + akc;
            float4 v0 = *(const float4*)pa, v1 = *(const float4*)(pa + 4);
            short4 h, l;
            split4(v0, h, l);
            *(short4*)&sAh[0][arow * 40 + akc] = h;
            *(short4*)&sAl[0][arow * 40 + akc] = l;
            split4(v1, h, l);
            *(short4*)&sAh[0][arow * 40 + akc + 4] = h;
            *(short4*)&sAl[0][arow * 40 + akc + 4] = l;
        }
        if (dual) {
            const float* pa = A1 + (size_t)(m0 + arow) * lda + kbase + kc + akc;
            float4 v0 = *(const float4*)pa, v1 = *(const float4*)(pa + 4);
            short4 h, l;
            split4(v0, h, l);
            *(short4*)&sAh[1][arow * 40 + akc] = h;
            *(short4*)&sAl[1][arow * 40 + akc] = l;
            split4(v1, h, l);
            *(short4*)&sAh[1][arow * 40 + akc + 4] = h;
            *(short4*)&sAl[1][arow * 40 + akc + 4] = l;
        }
        if (tid < 128) {
            int kk = tid >> 2, n4 = (tid & 3) * 4;
            float4 v = *(const float4*)(B0 + (size_t)(kbase + kc + kk) * 16 + n4);
            short4 h, l; split4(v, h, l);
            sBh[0][(n4 + 0) * 40 + kk] = h.x; sBh[0][(n4 + 1) * 40 + kk] = h.y;
            sBh[0][(n4 + 2) * 40 + kk] = h.z; sBh[0][(n4 + 3) * 40 + kk] = h.w;
            sBl[0][(n4 + 0) * 40 + kk] = l.x; sBl[0][(n4 + 1) * 40 + kk] = l.y;
            sBl[0][(n4 + 2) * 40 + kk] = l.z; sBl[0][(n4 + 3) * 40 + kk] = l.w;
        } else if (dual) {
            int t2 = tid - 128;
            int kk = t2 >> 2, n4 = (t2 & 3) * 4;
            float4 v = *(const float4*)(B1 + (size_t)(kbase + kc + kk) * 16 + n4);
            short4 h, l; split4(v, h, l);
            sBh[1][(n4 + 0) * 40 + kk] = h.x; sBh[1][(n4 + 1) * 40 + kk] = h.y;
            sBh[1][(n4 + 2) * 40 + kk] = h.z; sBh[1][(n4 + 3) * 40 + kk] = h.w;
            sBl[1][(n4 + 0) * 40 + kk] = l.x; sBl[1][(n4 + 1) * 40 + kk] = l.y;
            sBl[1][(n4 + 2) * 40 + kk] = l.z; sBl[1][(n4 + 3) * 40 + kk] = l.w;
        }
        __syncthreads();
        short8v ah0 = *(const short8v*)&sAh[0][(w * 16 + lr) * 40 + qd * 8];
        short8v al0 = *(const short8v*)&sAl[0][(w * 16 + lr) * 40 + qd * 8];
        short8v bh0 = *(const short8v*)&sBh[0][lr * 40 + qd * 8];
        short8v bl0 = *(const short8v*)&sBl[0][lr * 40 + qd * 8];
        acc = __builtin_amdgcn_mfma_f32_16x16x32_bf16(ah0, bh0, acc, 0, 0, 0);
        acc = __builtin_amdgcn_mfma_f32_16x16x32_bf16(ah0, bl0, acc, 0, 0, 0);
        acc = __builtin_amdgcn_mfma_f32_16x16x32_bf16(al0, bh0, acc, 0, 0, 0);
        if (dual) {
            short8v ah1 = *(const short8v*)&sAh[1][(w * 16 + lr) * 40 + qd * 8];
            short8v al1 = *(const short8v*)&sAl[1][(w * 16 + lr) * 40 + qd * 8];
            short8v bh1 = *(const short8v*)&sBh[1][lr * 40 + qd * 8];
            short8v bl1 = *(const short8v*)&sBl[1][lr * 40 + qd * 8];
            acc = __builtin_amdgcn_mfma_f32_16x16x32_bf16(ah1, bh1, acc, 0, 0, 0);
            acc = __builtin_amdgcn_mfma_f32_16x16x32_bf16(ah1, bl1, acc, 0, 0, 0);
            acc = __builtin_amdgcn_mfma_f32_16x16x32_bf16(al1, bh1, acc, 0, 0, 0);
        }
    }
    const int mb = m0 + w * 16 + qd * 4;
    #pragma unroll
    for (int r = 0; r < 4; ++r)
        atomicAdd(&C[(size_t)(mb + r) * ldc + lr], alpha * acc[r]);
}

// ---------------------------------------------------------------------------
// Trig matrices
// ---------------------------------------------------------------------------
__global__ void gen_trig(float* __restrict__ Cc, float* __restrict__ Sn,
                         float* __restrict__ D, float* __restrict__ I)
{
    size_t idx = (size_t)blockIdx.x * 256 + threadIdx.x;
    if (idx < 4194304) {
        int k = (int)(idx >> 11);
        int n = (int)(idx & 2047);
        int m = (k * n) & 2047;
        float ang = (float)((double)m * 0.0030679615757712823);  // 2pi/2048
        Cc[idx] = cosf(ang);
        Sn[idx] = -sinf(ang);
    } else {
        idx -= 4194304;
        int i = (int)(idx >> 11);
        int j = (int)(idx & 2047);
        const float r1 = 0.022097086912079608f;
        const float r2 = 0.03125f;
        const float pif = 3.14159265358979323846f;
        float a  = (pif * (float)i) * (float)(2 * j + 1) / 4096.0f;
        D[idx] = cosf(a) * (i == 0 ? r1 : r2);
        float ai = (pif * (float)j) * (float)(2 * i + 1) / 4096.0f;
        I[idx] = cosf(ai) * (j == 0 ? r1 : r2);
    }
}

// ---------------------------------------------------------------------------
// fw softmax (stored transposed, e-major) + G = (1/32) fw@fw^T. grid 3.
// ---------------------------------------------------------------------------
__launch_bounds__(256)
__global__ void prep_fw_G(const float* __restrict__ F0, const float* __restrict__ F1,
                          const float* __restrict__ F2, float* __restrict__ fwT,
                          float* __restrict__ G)
{
    const int d = blockIdx.x, tid = threadIdx.x;
    const float* Fp = d == 0 ? F0 : (d == 1 ? F1 : F2);
    __shared__ float sf[CC * 1028];
    #pragma unroll
    for (int k = 0; k < 4; ++k) {
        int e = tid + k * 256;
        float v[CC]; float m = -3.4e38f;
        #pragma unroll
        for (int c = 0; c < CC; ++c) { v[c] = Fp[c * EE + e]; m = fmaxf(m, v[c]); }
        float s = 0.f;
        #pragma unroll
        for (int c = 0; c < CC; ++c) { v[c] = expf(v[c] - m); s += v[c]; }
        float inv = 1.f / s;
        #pragma unroll
        for (int c = 0; c < CC; ++c) { v[c] *= inv; sf[c * 1028 + e] = v[c]; }
        #pragma unroll
        for (int j = 0; j < 4; ++j)
            *(float4*)(fwT + d * 16384 + (size_t)e * 16 + j * 4) = *(float4*)&v[j * 4];
    }
    __syncthreads();
    const int a = tid >> 4, b = tid & 15;
    const float4* pa = (const float4*)&sf[a * 1028];
    const float4* pb = (const float4*)&sf[b * 1028];
    float s = 0.f;
    for (int i = 0; i < 256; ++i) {
        float4 x = pa[i], y = pb[i];
        s += x.x * y.x + x.y * y.y + x.z * y.z + x.w * y.w;
    }
    G[d * 256 + a * 16 + b] = s * 0.03125f;
}

__global__ void build_w2(const float* __restrict__ W0, const float* __restrict__ W1,
                         const float* __restrict__ W2_, float* __restrict__ W2cat)
{
    int idx = blockIdx.x * 256 + threadIdx.x;
    if (idx >= 3 * CC * EE * 3) return;
    int d = idx / 49152, r = idx % 49152;
    const float* Wc = d == 0 ? W0 : (d == 1 ? W1 : W2_);
    int c = r / 3072, e = (r % 3072) / 3, k = r % 3;
    W2cat[d * 49152 + e * 48 + c * 3 + k] = Wc[r];
}

__global__ void build_ub2(const float* __restrict__ b0, const float* __restrict__ b1,
                          const float* __restrict__ b2, const float* __restrict__ W2cat,
                          float* __restrict__ ub)
{
    const int d = blockIdx.x, tid = threadIdx.x;
    const float* bp = d == 0 ? b0 : (d == 1 ? b1 : b2);
    __shared__ float red[4][48];
    const int c = tid & 63, sl = tid >> 6;
    float s = 0.f;
    if (c < 48)
        for (int e = sl; e < EE; e += 4)
            s += bp[e] * W2cat[d * 49152 + e * 48 + c];
    if (c < 48) red[sl][c] = s;
    __syncthreads();
    if (tid < 48) ub[d * 48 + tid] = red[0][tid] + red[1][tid] + red[2][tid] + red[3][tid];
}

__launch_bounds__(256)
__global__ void build_yb2(const float* __restrict__ ob, const float* __restrict__ fus_W,
                          const float* __restrict__ fus_b, float* __restrict__ yb)
{
    const int n = blockIdx.x * 4 + (threadIdx.x >> 6);
    const int lane = threadIdx.x & 63;
    float s = 0.f;
    for (int j = lane; j < 3072; j += 64)
        s += ob[j & 1023] * fus_W[(size_t)n * 3072 + j];
    #pragma unroll
    for (int off = 32; off > 0; off >>= 1) s += __shfl_xor(s, off, 64);
    if (lane == 0) yb[n] = s + fus_b[n];
}

// init: [W3cat 0 | Ucat=ub | Tfr,Tfi,Tc,Rf,Rc 0] + Pt 0 + FTb 0 + out=yb
__global__ void init_all(float* __restrict__ zone1, const float* __restrict__ ub,
                         float* __restrict__ Pt, float* __restrict__ FTb,
                         float* __restrict__ out, const float* __restrict__ yb)
{
    size_t idx = (size_t)blockIdx.x * 256 + threadIdx.x;
    const size_t W3N = 147456, UN = 589824, ZN = 720896;
    const size_t Z1 = W3N + UN + ZN;
    const size_t PTN = 156672, FTN = 3145728, ON = 4194304;
    if (idx < Z1) {
        float v = 0.f;
        if (idx >= W3N && idx < W3N + UN) {
            size_t r = idx - W3N;
            int d = (int)(r / 196608), c = (int)(r % 48);
            v = ub[d * 48 + c];
        }
        zone1[idx] = v;
    } else if (idx < Z1 + PTN) {
        Pt[idx - Z1] = 0.f;
    } else if (idx < Z1 + PTN + FTN) {
        FTb[idx - Z1 - PTN] = 0.f;
    } else if (idx < Z1 + PTN + FTN + ON) {
        size_t r = idx - Z1 - PTN - FTN;
        out[r] = yb[r & 1023];
    }
}

__global__ void ib_append(const float* __restrict__ ib, float* __restrict__ Pt)
{
    int idx = blockIdx.x * 256 + threadIdx.x;
    if (idx >= 9216) return;
    int d = idx / 3072, j = idx % 3072;
    Pt[d * 52224 + j * 17 + 16] = ib[j];
}

__launch_bounds__(256)
__global__ void build_M(const float* __restrict__ Pt, float* __restrict__ Mten)
{
    int blk = blockIdx.x;             // h*9 + l*3 + m
    int h = blk / 9, lm = blk % 9;
    int l = lm / 3, m = lm % 3;
    __shared__ float sQ[64][17], sK[64][17];
    for (int lin = threadIdx.x; lin < 1088; lin += 256) {
        int d = lin / 17, a = lin % 17;
        sQ[d][a] = Pt[l * 52224 + (size_t)(h * 64 + d) * 17 + a];
        sK[d][a] = Pt[m * 52224 + (size_t)(1024 + h * 64 + d) * 17 + a];
    }
    __syncthreads();
    for (int o = threadIdx.x; o < 289; o += 256) {
        int a = o / 17, b = o % 17;
        float s = 0.f;
        for (int d = 0; d < 64; ++d) s += sQ[d][a] * sK[d][b];
        Mten[(size_t)blk * 289 + o] = 0.125f * s;
    }
}

__global__ void transpose_k(const float* __restrict__ X, float* __restrict__ XT,
                            int rows, int cols)
{
    __shared__ float tile[32][33];
    const int lx = threadIdx.x & 31, ly = threadIdx.x >> 5;
    const int r0 = blockIdx.y * 32, c0 = blockIdx.x * 32;
    #pragma unroll
    for (int p = 0; p < 4; ++p)
        tile[ly + p * 8][lx] = X[(size_t)(r0 + ly + p * 8) * cols + c0 + lx];
    __syncthreads();
    #pragma unroll
    for (int p = 0; p < 4; ++p)
        XT[(size_t)(c0 + ly + p * 8) * rows + r0 + lx] = tile[lx][ly + p * 8];
}

__global__ void transpose_wp3(const float* __restrict__ W0, const float* __restrict__ W1,
                              const float* __restrict__ W2, float* __restrict__ WT)
{
    __shared__ float tile[32][33];
    const float* X = blockIdx.z == 0 ? W0 : (blockIdx.z == 1 ? W1 : W2);
    float* T = WT + (size_t)blockIdx.z * 1048576;
    const int lx = threadIdx.x & 31, ly = threadIdx.x >> 5;
    const int r0 = blockIdx.y * 32, c0 = blockIdx.x * 32;
    #pragma unroll
    for (int p = 0; p < 4; ++p)
        tile[ly + p * 8][lx] = X[(size_t)(r0 + ly + p * 8) * 1024 + c0 + lx];
    __syncthreads();
    #pragma unroll
    for (int p = 0; p < 4; ++p)
        T[(size_t)(c0 + ly + p * 8) * 1024 + r0 + lx] = tile[lx][ly + p * 8];
}

// ---------------------------------------------------------------------------
// Full Haar pyramid, one kernel. grid (48/HCG, B).
// ---------------------------------------------------------------------------
#define HCG 4
__launch_bounds__(256)
__global__ void haar_all(const float* __restrict__ U, float* __restrict__ T)
{
    __shared__ float A[2048 * HCG];
    __shared__ float Pp[1024 * HCG];
    const int g = blockIdx.x, b = blockIdx.y, tid = threadIdx.x;
    const float isq = 0.70710678118654752440f;
    for (int lin = tid; lin < 2048; lin += 256)
        *(float4*)&A[lin * 4] = *(const float4*)(U + ((size_t)(b * 2048 + lin)) * 48 + g * HCG);
    __syncthreads();
    float* cur = A; float* nxt = Pp;
    for (int h = 1024; h >= 1; h >>= 1) {
        for (int lin = tid; lin < h * HCG; lin += 256) {
            int i = lin >> 2, c = lin & 3;
            float e = cur[(2 * i) * HCG + c], o = cur[(2 * i + 1) * HCG + c];
            T[((size_t)(b * 2048 + h + i)) * 48 + g * HCG + c] = (e - o) * isq;
            nxt[i * HCG + c] = (e + o) * isq;
        }
        __syncthreads();
        float* t = cur; cur = nxt; nxt = t;
    }
    if (tid < HCG) T[((size_t)(b * 2048)) * 48 + g * HCG + tid] = cur[tid];
}

// ---------------------------------------------------------------------------
// conv collapse + G fold, all 3 domains in one launch. grid (32, B, 3).
// ---------------------------------------------------------------------------
__launch_bounds__(256)
__global__ void conv_all(const float* __restrict__ Tfr, const float* __restrict__ Tfi,
                         const float* __restrict__ Tw, const float* __restrict__ Tc,
                         const float* __restrict__ Gm,
                         const float* __restrict__ bc0, const float* __restrict__ bc1,
                         const float* __restrict__ bc2,
                         float* __restrict__ chFr, float* __restrict__ chFi,
                         float* __restrict__ chW, float* __restrict__ chC,
                         float* __restrict__ QFr, float* __restrict__ QFi,
                         float* __restrict__ QW, float* __restrict__ QC)
{
    const int dom = blockIdx.z;
    const bool cplx = (dom == 0);
    const float* Tre = dom == 0 ? Tfr : (dom == 1 ? Tw : Tc);
    const float* Tim = Tfi;
    const float* G = Gm + dom * 256;
    const float* bc = dom == 0 ? bc0 : (dom == 1 ? bc1 : bc2);
    float* chR = dom == 0 ? chFr : (dom == 1 ? chW : chC);
    float* chI = chFi;
    float* QR = dom == 0 ? QFr : (dom == 1 ? QW : QC);
    float* QI = QFi;

    const int s0 = blockIdx.x * 64, b = blockIdx.y;
    const int tid = threadIdx.x;
    __shared__ float sR[66 * 49];
    __shared__ float sI[66 * 49];
    __shared__ float scr[64 * 17];
    __shared__ float sci[64 * 17];
    __shared__ float sG[256];
    if (tid < 256) sG[tid] = G[tid];
    for (int lin = tid; lin < 66 * 12; lin += 256) {
        int r = lin / 12, c4 = (lin % 12) * 4;
        int srow = s0 - 1 + r;
        float4 v = {0.f, 0.f, 0.f, 0.f}, w = {0.f, 0.f, 0.f, 0.f};
        if (srow >= 0 && srow < 2048) {
            v = *(const float4*)(Tre + ((size_t)(b * 2048 + srow)) * 48 + c4);
            if (cplx) w = *(const float4*)(Tim + ((size_t)(b * 2048 + srow)) * 48 + c4);
        }
        sR[r * 49 + c4] = v.x; sR[r * 49 + c4 + 1] = v.y;
        sR[r * 49 + c4 + 2] = v.z; sR[r * 49 + c4 + 3] = v.w;
        if (cplx) {
            sI[r * 49 + c4] = w.x; sI[r * 49 + c4 + 1] = w.y;
            sI[r * 49 + c4 + 2] = w.z; sI[r * 49 + c4 + 3] = w.w;
        }
    }
    __syncthreads();
    const int row = tid >> 2, ln = tid & 3;
    float ch[4], chi[4];
    #pragma unroll
    for (int j = 0; j < 4; ++j) {
        int c = ln * 4 + j;
        float bcv = bc[c];
        ch[j] = sR[row * 49 + 3 * c] + sR[(row + 1) * 49 + 3 * c + 1]
              + sR[(row + 2) * 49 + 3 * c + 2] + bcv;
        scr[row * 17 + c] = ch[j];
        if (cplx) {
            chi[j] = sI[row * 49 + 3 * c] + sI[(row + 1) * 49 + 3 * c + 1]
                   + sI[(row + 2) * 49 + 3 * c + 2] + bcv;
            sci[row * 17 + c] = chi[j];
        }
    }
    size_t ro = ((size_t)(b * 2048 + s0 + row)) * 16 + ln * 4;
    *(float4*)(chR + ro) = *(float4*)&ch[0];
    if (cplx) *(float4*)(chI + ro) = *(float4*)&chi[0];
    __syncthreads();
    float qp[4] = {}, qpi[4] = {};
    #pragma unroll
    for (int c = 0; c < 16; ++c) {
        float cv = scr[row * 17 + c];
        float cvi = cplx ? sci[row * 17 + c] : 0.f;
        #pragma unroll
        for (int j = 0; j < 4; ++j) {
            float g = sG[c * 16 + ln * 4 + j];
            qp[j] = fmaf(cv, g, qp[j]);
            if (cplx) qpi[j] = fmaf(cvi, g, qpi[j]);
        }
    }
    *(float4*)(QR + ro) = *(float4*)&qp[0];
    if (cplx) *(float4*)(QI + ro) = *(float4*)&qpi[0];
}

// ---------------------------------------------------------------------------
// Flash v4.
// Real (z=1,2): 2 rows/wave, 8-key tiles, deferred rescale. grid.x < 256.
// Complex (z=0): 1 row/wave, 4-key tiles, deferred rescale. grid.x < 512.
// grid (512, B, 3).
// ---------------------------------------------------------------------------
__device__ __forceinline__ float dot16(const float q[16], const float k[16])
{
    float a = q[0] * k[0], b = q[1] * k[1], c = q[2] * k[2], d = q[3] * k[3];
    a = fmaf(q[4], k[4], a);  b = fmaf(q[5], k[5], b);
    c = fmaf(q[6], k[6], c);  d = fmaf(q[7], k[7], d);
    a = fmaf(q[8], k[8], a);  b = fmaf(q[9], k[9], b);
    c = fmaf(q[10], k[10], c); d = fmaf(q[11], k[11], d);
    a = fmaf(q[12], k[12], a); b = fmaf(q[13], k[13], b);
    c = fmaf(q[14], k[14], c); d = fmaf(q[15], k[15], d);
    return (a + b) + (c + d);
}

__device__ __forceinline__ void cdot16(const float qr[16], const float qi[16],
                                       const float kr[16], const float ki[16],
                                       float& sre, float& sim)
{
    float a = 0.f, b = 0.f, c = 0.f, d = 0.f;
    float e2 = 0.f, f = 0.f, g = 0.f, h = 0.f;
    #pragma unroll
    for (int e = 0; e < 8; ++e) {
        a = fmaf(qr[e], kr[e], a);
        b = fmaf(qr[e + 8], kr[e + 8], b);
        c = fmaf(qi[e], ki[e], c);
        d = fmaf(qi[e + 8], ki[e + 8], d);
        e2 = fmaf(qr[e], ki[e], e2);
        f = fmaf(qr[e + 8], ki[e + 8], f);
        g = fmaf(qi[e], kr[e], g);
        h = fmaf(qi[e + 8], kr[e + 8], h);
    }
    sre = (a + b) - (c + d);
    sim = (e2 + f) + (g + h);
}

__launch_bounds__(256)
__global__ void flash_v4(const float* __restrict__ QpFr, const float* __restrict__ QpFi,
                         const float* __restrict__ chFr, const float* __restrict__ chFi,
                         float* __restrict__ OFr, float* __restrict__ OFi,
                         const float* __restrict__ QpW, const float* __restrict__ chW,
                         float* __restrict__ Ow_,
                         const float* __restrict__ QpC, const float* __restrict__ chC,
                         float* __restrict__ Oc_)
{
    const int dom = blockIdx.z, b = blockIdx.y;
    const int w = threadIdx.x >> 6, lane = threadIdx.x & 63;
    if (dom != 0) {
        if (blockIdx.x >= 256) return;
        const float* Qp = dom == 1 ? QpW : QpC;
        const float* ch = dom == 1 ? chW : chC;
        float* O = dom == 1 ? Ow_ : Oc_;
        const int s0 = blockIdx.x * 8 + w * 2;
        float q0[16], q1[16];
        {
            const float* qr0 = Qp + ((size_t)(b * 2048 + s0)) * 16;
            #pragma unroll
            for (int j = 0; j < 4; ++j) {
                *(float4*)&q0[j * 4] = *(const float4*)(qr0 + j * 4);
                *(float4*)&q1[j * 4] = *(const float4*)(qr0 + 16 + j * 4);
            }
        }
        const float* chb = ch + (size_t)b * 2048 * 16;
        float m0 = -3.4e38f, m1 = -3.4e38f, l0 = 0.f, l1 = 0.f;
        float a0[16] = {}, a1[16] = {};
        for (int t0 = 0; t0 < 2048; t0 += 512) {
            float sv0[8], sv1[8];
            #pragma unroll
            for (int j = 0; j < 8; ++j) {
                const float* kp = chb + (size_t)(t0 + j * 64 + lane) * 16;
                float kv[16];
                #pragma unroll
                for (int i = 0; i < 4; ++i) *(float4*)&kv[i * 4] = *(const float4*)(kp + i * 4);
                sv0[j] = dot16(q0, kv);
                sv1[j] = dot16(q1, kv);
            }
            float tm0 = fmaxf(fmaxf(fmaxf(sv0[0], sv0[1]), fmaxf(sv0[2], sv0[3])),
                              fmaxf(fmaxf(sv0[4], sv0[5]), fmaxf(sv0[6], sv0[7])));
            float tm1 = fmaxf(fmaxf(fmaxf(sv1[0], sv1[1]), fmaxf(sv1[2], sv1[3])),
                              fmaxf(fmaxf(sv1[4], sv1[5]), fmaxf(sv1[6], sv1[7])));
            float nm0 = fmaxf(m0, tm0), nm1 = fmaxf(m1, tm1);
            float al0 = __expf(m0 - nm0), al1 = __expf(m1 - nm1);
            l0 *= al0; l1 *= al1;
            #pragma unroll
            for (int e = 0; e < 16; ++e) { a0[e] *= al0; a1[e] *= al1; }
            m0 = nm0; m1 = nm1;
            #pragma unroll
            for (int j = 0; j < 8; ++j) {
                const float* kp = chb + (size_t)(t0 + j * 64 + lane) * 16;
                float kv[16];
                #pragma unroll
                for (int i = 0; i < 4; ++i) *(float4*)&kv[i * 4] = *(const float4*)(kp + i * 4);
                float p0 = __expf(sv0[j] - m0);
                float p1 = __expf(sv1[j] - m1);
                l0 += p0; l1 += p1;
                #pragma unroll
                for (int e = 0; e < 16; ++e) {
                    a0[e] = fmaf(p0, kv[e], a0[e]);
                    a1[e] = fmaf(p1, kv[e], a1[e]);
                }
            }
        }
        #pragma unroll
        for (int off = 1; off < 64; off <<= 1) {
            float mm = __shfl_xor(m0, off, 64), ll = __shfl_xor(l0, off, 64);
            float mn = fmaxf(m0, mm);
            float ra = __expf(m0 - mn), rb = __expf(mm - mn);
            l0 = l0 * ra + ll * rb;
            #pragma unroll
            for (int e = 0; e < 16; ++e) {
                float x = __shfl_xor(a0[e], off, 64);
                a0[e] = a0[e] * ra + x * rb;
            }
            m0 = mn;
            mm = __shfl_xor(m1, off, 64); ll = __shfl_xor(l1, off, 64);
            mn = fmaxf(m1, mm);
            ra = __expf(m1 - mn); rb = __expf(mm - mn);
            l1 = l1 * ra + ll * rb;
            #pragma unroll
            for (int e = 0; e < 16; ++e) {
                float x = __shfl_xor(a1[e], off, 64);
                a1[e] = a1[e] * ra + x * rb;
            }
            m1 = mn;
        }
        if (lane < 4) {
            float inv = 1.f / l0;
            float4 o4 = {a0[lane * 4] * inv, a0[lane * 4 + 1] * inv,
                         a0[lane * 4 + 2] * inv, a0[lane * 4 + 3] * inv};
            *(float4*)(O + ((size_t)(b * 2048 + s0)) * 16 + lane * 4) = o4;
        } else if (lane < 8) {
            int j = lane - 4;
            float inv = 1.f / l1;
            float4 o4 = {a1[j * 4] * inv, a1[j * 4 + 1] * inv,
                         a1[j * 4 + 2] * inv, a1[j * 4 + 3] * inv};
            *(float4*)(O + ((size_t)(b * 2048 + s0 + 1)) * 16 + j * 4) = o4;
        }
        return;
    }
    // ---- complex, 1 row per wave, 4-key tiles ----
    const int s = blockIdx.x * 4 + w;
    float qr[16], qi[16];
    {
        const float* qrow = QpFr + ((size_t)(b * 2048 + s)) * 16;
        const float* qrowI = QpFi + ((size_t)(b * 2048 + s)) * 16;
        #pragma unroll
        for (int j = 0; j < 4; ++j) {
            *(float4*)&qr[j * 4] = *(const float4*)(qrow + j * 4);
            *(float4*)&qi[j * 4] = *(const float4*)(qrowI + j * 4);
        }
    }
    const float* cbR = chFr + (size_t)b * 2048 * 16;
    const float* cbI = chFi + (size_t)b * 2048 * 16;
    float m = -3.4e38f, l = 0.f;
    float aR[16] = {}, aI[16] = {};
    for (int t0 = 0; t0 < 2048; t0 += 256) {
        float svr[4], svi[4];
        #pragma unroll
        for (int j = 0; j < 4; ++j) {
            const size_t ko = (size_t)(t0 + j * 64 + lane) * 16;
            float kr[16], ki[16];
            #pragma unroll
            for (int i = 0; i < 4; ++i) {
                *(float4*)&kr[i * 4] = *(const float4*)(cbR + ko + i * 4);
                *(float4*)&ki[i * 4] = *(const float4*)(cbI + ko + i * 4);
            }
            cdot16(qr, qi, kr, ki, svr[j], svi[j]);
        }
        float tm = fmaxf(fmaxf(svr[0], svr[1]), fmaxf(svr[2], svr[3]));
        float nm = fmaxf(m, tm);
        float al = __expf(m - nm);
        l *= al;
        #pragma unroll
        for (int e = 0; e < 16; ++e) { aR[e] *= al; aI[e] *= al; }
        m = nm;
        #pragma unroll
        for (int j = 0; j < 4; ++j) {
            const size_t ko = (size_t)(t0 + j * 64 + lane) * 16;
            float kr[16], ki[16];
            #pragma unroll
            for (int i = 0; i < 4; ++i) {
                *(float4*)&kr[i * 4] = *(const float4*)(cbR + ko + i * 4);
                *(float4*)&ki[i * 4] = *(const float4*)(cbI + ko + i * 4);
            }
            float p = __expf(svr[j] - m);
            l += p;
            float rr = sqrtf(svr[j] * svr[j] + svi[j] * svi[j]);
            float iv = (rr > 0.f) ? (p / rr) : 0.f;
            float wr = (rr > 0.f) ? iv * svr[j] : p;
            float wi = (rr > 0.f) ? iv * svi[j] : 0.f;
            #pragma unroll
            for (int e = 0; e < 16; ++e) {
                aR[e] = fmaf(wr, kr[e], aR[e]);
                aR[e] = fmaf(-wi, ki[e], aR[e]);
                aI[e] = fmaf(wr, ki[e], aI[e]);
                aI[e] = fmaf(wi, kr[e], aI[e]);
            }
        }
    }
    #pragma unroll
    for (int off = 1; off < 64; off <<= 1) {
        float m2 = __shfl_xor(m, off, 64);
        float l2 = __shfl_xor(l, off, 64);
        float mn = fmaxf(m, m2);
        float ra = __expf(m - mn), rb = __expf(m2 - mn);
        l = l * ra + l2 * rb;
        #pragma unroll
        for (int e = 0; e < 16; ++e) {
            float x = __shfl_xor(aR[e], off, 64);
            aR[e] = aR[e] * ra + x * rb;
            float y = __shfl_xor(aI[e], off, 64);
            aI[e] = aI[e] * ra + y * rb;
        }
        m = mn;
    }
    float inv = 1.f / l;
    size_t ro = ((size_t)(b * 2048 + s)) * 16;
    if (lane < 4) {
        float4 o4 = {aR[lane * 4] * inv, aR[lane * 4 + 1] * inv,
                     aR[lane * 4 + 2] * inv, aR[lane * 4 + 3] * inv};
        *(float4*)(OFr + ro + lane * 4) = o4;
    } else if (lane < 8) {
        int j = lane - 4;
        float4 o4 = {aI[j * 4] * inv, aI[j * 4 + 1] * inv,
                     aI[j * 4 + 2] * inv, aI[j * 4 + 3] * inv};
        *(float4*)(OFi + ro + j * 4) = o4;
    }
}

// ---------------------------------------------------------------------------
// MHA over L=3 via rank-17 bilinear forms -> MO (4096, 3072). grid (16,16).
// ---------------------------------------------------------------------------
__launch_bounds__(256)
__global__ void mha_o(const float* __restrict__ R0, const float* __restrict__ R1,
                      const float* __restrict__ R2, const float* __restrict__ Pt,
                      const float* __restrict__ Mten, float* __restrict__ MO)
{
    const int tid = threadIdx.x;
    const int p = blockIdx.x * 256 + tid;
    const int h = blockIdx.y;
    __shared__ float sPv[3 * 64 * 20];
    __shared__ float sM[9 * 17 * 20];
    for (int lin = tid; lin < 3264; lin += 256) {
        int mm = lin / 1088, rem = lin % 1088;
        int rr = rem / 17, a = rem % 17;
        sPv[(mm * 64 + rr) * 20 + a] = Pt[mm * 52224 + (size_t)(2048 + h * 64 + rr) * 17 + a];
    }
    for (int lin = tid; lin < 2601; lin += 256) {
        int lm = lin / 289, rem = lin % 289;
        int a = rem / 17, bq = rem % 17;
        sM[lm * 340 + a * 20 + bq] = Mten[(size_t)h * 2601 + lin];
    }
    __syncthreads();
    float R[3][16];
    float4 R4[3][4];
    #pragma unroll
    for (int j = 0; j < 4; ++j) {
        R4[0][j] = *(const float4*)(R0 + (size_t)p * 16 + j * 4);
        R4[1][j] = *(const float4*)(R1 + (size_t)p * 16 + j * 4);
        R4[2][j] = *(const float4*)(R2 + (size_t)p * 16 + j * 4);
        *(float4*)&R[0][j * 4] = R4[0][j];
        *(float4*)&R[1][j * 4] = R4[1][j];
        *(float4*)&R[2][j * 4] = R4[2][j];
    }
    float w[3][3];
    #pragma unroll
    for (int l = 0; l < 3; ++l) {
        float sc[3];
        #pragma unroll
        for (int mm = 0; mm < 3; ++mm) {
            const float* Mp = &sM[(l * 3 + mm) * 340];
            float s = 0.f;
            #pragma unroll
            for (int a = 0; a < 17; ++a) {
                const float* mr = Mp + a * 20;
                float4 m0 = *(const float4*)(mr), m1 = *(const float4*)(mr + 4);
                float4 m2 = *(const float4*)(mr + 8), m3 = *(const float4*)(mr + 12);
                float t = mr[16];
                t = fmaf(m0.x, R4[mm][0].x, t); t = fmaf(m0.y, R4[mm][0].y, t);
                t = fmaf(m0.z, R4[mm][0].z, t); t = fmaf(m0.w, R4[mm][0].w, t);
                t = fmaf(m1.x, R4[mm][1].x, t); t = fmaf(m1.y, R4[mm][1].y, t);
                t = fmaf(m1.z, R4[mm][1].z, t); t = fmaf(m1.w, R4[mm][1].w, t);
                t = fmaf(m2.x, R4[mm][2].x, t); t = fmaf(m2.y, R4[mm][2].y, t);
                t = fmaf(m2.z, R4[mm][2].z, t); t = fmaf(m2.w, R4[mm][2].w, t);
                t = fmaf(m3.x, R4[mm][3].x, t); t = fmaf(m3.y, R4[mm][3].y, t);
                t = fmaf(m3.z, R4[mm][3].z, t); t = fmaf(m3.w, R4[mm][3].w, t);
                float ra = (a < 16) ? R[l][a] : 1.f;
                s = fmaf(ra, t, s);
            }
            sc[mm] = s;
        }
        float mx = fmaxf(sc[0], fmaxf(sc[1], sc[2]));
        float e0 = expf(sc[0] - mx), e1 = expf(sc[1] - mx), e2 = expf(sc[2] - mx);
        float inv = 1.f / (e0 + e1 + e2);
        w[l][0] = e0 * inv; w[l][1] = e1 * inv; w[l][2] = e2 * inv;
    }
    #pragma unroll
    for (int d4 = 0; d4 < 16; ++d4) {
        float4 vm[3];
        #pragma unroll
        for (int mm = 0; mm < 3; ++mm) {
            float vx[4];
            #pragma unroll
            for (int r = 0; r < 4; ++r) {
                const float* pv = &sPv[(mm * 64 + d4 * 4 + r) * 20];
                float4 p0 = *(const float4*)(pv), p1 = *(const float4*)(pv + 4);
                float4 p2 = *(const float4*)(pv + 8), p3 = *(const float4*)(pv + 12);
                float t = pv[16];
                t = fmaf(R4[mm][0].x, p0.x, t); t = fmaf(R4[mm][0].y, p0.y, t);
                t = fmaf(R4[mm][0].z, p0.z, t); t = fmaf(R4[mm][0].w, p0.w, t);
                t = fmaf(R4[mm][1].x, p1.x, t); t = fmaf(R4[mm][1].y, p1.y, t);
                t = fmaf(R4[mm][1].z, p1.z, t); t = fmaf(R4[mm][1].w, p1.w, t);
                t = fmaf(R4[mm][2].x, p2.x, t); t = fmaf(R4[mm][2].y, p2.y, t);
                t = fmaf(R4[mm][2].z, p2.z, t); t = fmaf(R4[mm][2].w, p2.w, t);
                t = fmaf(R4[mm][3].x, p3.x, t); t = fmaf(R4[mm][3].y, p3.y, t);
                t = fmaf(R4[mm][3].z, p3.z, t); t = fmaf(R4[mm][3].w, p3.w, t);
                vx[r] = t;
            }
            vm[mm] = (float4){vx[0], vx[1], vx[2], vx[3]};
        }
        #pragma unroll
        for (int l = 0; l < 3; ++l) {
            float4 o4;
            o4.x = w[l][0] * vm[0].x + w[l][1] * vm[1].x + w[l][2] * vm[2].x;
            o4.y = w[l][0] * vm[0].y + w[l][1] * vm[1].y + w[l][2] * vm[2].y;
            o4.z = w[l][0] * vm[0].z + w[l][1] * vm[1].z + w[l][2] * vm[2].z;
            o4.w = w[l][0] * vm[0].w + w[l][1] * vm[1].w + w[l][2] * vm[2].w;
            *(float4*)(MO + (size_t)p * 3072 + l * 1024 + h * 64 + d4 * 4) = o4;
        }
    }
}

// ---------------------------------------------------------------------------
// Host
// ---------------------------------------------------------------------------
extern "C" void kernel_launch(void* const* d_in, const int* in_sizes, int n_in,
                              void* d_out, int out_size, void* d_ws, size_t ws_size,
                              hipStream_t stream)
{
    const float* query = (const float*)d_in[0];
    const float* Wp[3] = {(const float*)d_in[1], (const float*)d_in[6],  (const float*)d_in[11]};
    const float* bp[3] = {(const float*)d_in[2], (const float*)d_in[7],  (const float*)d_in[12]};
    const float* Wc[3] = {(const float*)d_in[3], (const float*)d_in[8],  (const float*)d_in[13]};
    const float* bc[3] = {(const float*)d_in[4], (const float*)d_in[9],  (const float*)d_in[14]};
    const float* Fp[3] = {(const float*)d_in[5], (const float*)d_in[10], (const float*)d_in[15]};
    const float* mha_iw = (const float*)d_in[16];
    const float* mha_ib = (const float*)d_in[17];
    const float* mha_ow = (const float*)d_in[18];
    const float* mha_ob = (const float*)d_in[19];
    const float* fus_W  = (const float*)d_in[20];
    const float* fus_b  = (const float*)d_in[21];
    float* out = (float*)d_out;
    float* ws = (float*)d_ws;

    size_t off = 0;
    auto alloc = [&](size_t n) { float* p = ws + off; off += n; return p; };
    float* MAT0 = alloc(4194304);
    float* MAT1 = alloc(4194304);
    float* DCTD = alloc(4194304);
    float* DCTI = alloc(4194304);
    float* MO   = alloc((size_t)4096 * 3072);
    float* FTb  = alloc((size_t)1024 * 3072);
    float* OWT  = alloc((size_t)1024 * 1024);
    float* WpT  = alloc(3145728);
    float* fwT  = alloc(49152);
    float* W2cat = alloc(147456);
    float* ubv  = alloc(256);
    float* Gm   = alloc(1024);
    float* W3cat = alloc(147456);     // contiguous init region start
    float* Ucat = alloc(589824);
    float* Tfr  = alloc(196608);
    float* Tfi  = alloc(196608);
    float* Tc   = alloc(196608);
    float* Rf   = alloc(65536);
    float* Rc   = alloc(65536);       // init region end
    float* Tw   = alloc(196608);
    float* chFr = alloc(65536); float* chFi = alloc(65536);
    float* QpFr = alloc(65536); float* QpFi = alloc(65536);
    float* chW  = alloc(65536); float* QpW  = alloc(65536);
    float* chC  = alloc(65536); float* QpC  = alloc(65536);
    float* OFr  = alloc(65536); float* OFi  = alloc(65536);
    float* Ow   = alloc(65536); float* Oc   = alloc(65536);
    float* Pt   = alloc(156672);
    float* Mten = alloc(41616);
    float* ybv  = alloc(1024);
    if (ws_size < off * sizeof(float)) return;

    float* Uf = Ucat, *Uw = Ucat + 196608, *Uc = Ucat + 2 * 196608;

    // ---- prep ----
    build_w2<<<dim3(576), dim3(256), 0, stream>>>(Wc[0], Wc[1], Wc[2], W2cat);
    prep_fw_G<<<dim3(3), dim3(256), 0, stream>>>(Fp[0], Fp[1], Fp[2], fwT, Gm);
    build_ub2<<<dim3(3), dim3(256), 0, stream>>>(bp[0], bp[1], bp[2], W2cat, ubv);
    build_yb2<<<dim3(256), dim3(256), 0, stream>>>(mha_ob, fus_W, fus_b, ybv);
    gen_trig<<<dim3(32768), dim3(256), 0, stream>>>(MAT0, MAT1, DCTD, DCTI);
    transpose_wp3<<<dim3(32, 32, 3), dim3(256), 0, stream>>>(Wp[0], Wp[1], Wp[2], WpT);
    init_all<<<dim3(34980), dim3(256), 0, stream>>>(W3cat, ubv, Pt, FTb, out, ybv);

    // W3_d = Wp_d^T @ W2_d   (K=1024, KS=2)
    sk48<<<dim3(16, 1, 6), dim3(256), 0, stream>>>(
        WpT, W2cat, W3cat, 1024, 1048576, 49152, 49152, 2);
    // U_d = query @ W3_d (+ub preloaded)   (K=1024, KS=2)
    sk48<<<dim3(64, 1, 6), dim3(256), 0, stream>>>(
        query, W3cat, Ucat, 1024, 0, 49152, 196608, 2);

    // forward transforms: fourier(dual) + dct in one launch
    skinny_fwd<<<dim3(32, 1, 16), dim3(256), 0, stream>>>(
        MAT0, MAT1, DCTD, Uf, Uc, Tfr, Tfi, Tc);

    // Haar pyramid
    haar_all<<<dim3(12, 2), dim3(256), 0, stream>>>(Uw, Tw);

    // conv collapse + G fold (all domains)
    conv_all<<<dim3(32, 2, 3), dim3(256), 0, stream>>>(
        Tfr, Tfi, Tw, Tc, Gm, bc[0], bc[1], bc[2],
        chFr, chFi, chW, chC, QpFr, QpFi, QpW, QpC);

    // flash attentions (all domains)
    flash_v4<<<dim3(512, 2, 3), dim3(256), 0, stream>>>(
        QpFr, QpFi, chFr, chFi, OFr, OFi, QpW, chW, Ow, QpC, chC, Oc);

    // inverse transforms + Pt in one launch
    skinny_inv<<<dim3(48, 1, 22), dim3(256), 0, stream>>>(
        MAT0, MAT1, DCTI, OFr, OFi, Oc, mha_iw, fwT, Rf, Rc, Pt);

    ib_append<<<dim3(36), dim3(256), 0, stream>>>(mha_ib, Pt);
    build_M<<<dim3(144), dim3(256), 0, stream>>>(Pt, Mten);

    // MHA core -> MO (4096, 3072)
    mha_o<<<dim3(16, 16), dim3(256), 0, stream>>>(Rf, Ow, Rc, Pt, Mten, MO);

    // FT_l = fusW_l @ ow  (atomic K-split 4, FTb pre-zeroed)
    transpose_k<<<dim3(32, 32), dim3(256), 0, stream>>>(mha_ow, OWT, 1024, 1024);
    gemm_at<<<dim3(8, 8, 12), dim3(256), 0, stream>>>(
        fus_W, OWT, FTb, 1024, 3072, 1024, 3072, 1024, 0, 1024, 1.f, 4);

    // out = MO @ FTb^T + yb  (out pre-initialized with yb; atomic K-split 4)
    gemm_at<<<dim3(8, 32, 4), dim3(256), 0, stream>>>(
        MO, FTb, out, 3072, 3072, 3072, 1024, 0, 0, 0, 1.f, 4);
}